// Round 6
// baseline (231.811 us; speedup 1.0000x reference)
//
#include <hip/hip_runtime.h>
#include <math.h>

// PCEN: x[B=64, C=128, T=4000] fp32.
// smooth[0]=x[0]; smooth[t]=(1-s)*smooth[t-1]+s*x[t], s=0.025
// out = sqrt(x/(smooth+1e-6)^0.98 + 2) - sqrt(2)
//
// R6 = R5 with the nontemporal-store compile fix (native ext_vector_type(4)
// instead of HIP's float4 class). Theory under test (from R0-R4 evidence):
// PERSISTENT WAVES IN STEADY STATE. R0-R4 falsified VALU-issue, MLP,
// barrier, and (compiler-collapsed) intra-wave pipelining theories; dur was
// pinned at ~80us with HBM at 31% while fillBuffer hit 6.6 TB/s at 9%
// occupancy on the same device. Common property of all failures: one-shot
// waves (load burst -> wait -> compute -> store -> die), device-wide
// phase-lock. Here 4096 waves each process TWO channels as FOUR half-channel
// stages (8 scan columns each; the scan is column-independent and the e-carry
// is sequential anyway -> bit-identical math to R3). Loads for stage s+1 are
// issued into the alternate register buffer and PINNED above stage s's
// compute with __builtin_amdgcn_sched_barrier(0) (R4's pipeline died because
// the allocator sank the loads; 2x8 float4 buffers fit in ~110 VGPR).
// Output is written with nontemporal stores (never re-read; don't evict the
// input's LLC-resident half).

constexpr int   TLEN = 4000;
constexpr int   NF4  = 1000;   // float4 chunks per channel
constexpr int   NTH  = 256;
constexpr int   HALF = 8;      // scan columns per stage (half channel)
constexpr float S_C  = 0.025f;
constexpr float A_1  = 1.0f - S_C;

typedef float f4_t __attribute__((ext_vector_type(4)));   // native vec for nt-store

constexpr float fpow(float b, int n) {
    float r = 1.0f;
    for (int i = 0; i < n; ++i) r *= b;
    return r;
}
constexpr float A_2  = fpow(A_1, 2);
constexpr float A_3  = fpow(A_1, 3);
constexpr float A256 = fpow(A_1, 256);   // one segment = 64 lanes * 4 elems

// 4*log2(1-s): per-lane exclusive coefficient is exp2(lane * L2A4)
constexpr float L2A4 = -0.14610359f;

constexpr float ALPHA = 0.98f;
constexpr float EPS_C = 1e-6f;
constexpr float SQRT2 = 1.41421356237309515f;

__device__ __forceinline__ float pcen_elem(float x, float sm) {
    float t = sm + EPS_C;
    float p = __builtin_amdgcn_exp2f(-ALPHA * __builtin_amdgcn_logf(t)); // t^-alpha
    float y = fmaf(x, p, 2.0f);
    return __builtin_amdgcn_sqrtf(y) - SQRT2;
}

__device__ __forceinline__ void load_half(f4_t (&v)[HALF], const f4_t* __restrict__ x4,
                                          int lane, int h /*compile-time*/) {
#pragma unroll
    for (int j = 0; j < HALF; ++j) {
        const int f4 = lane + 64 * (h * HALF + j);
        v[j] = (f4 < NF4) ? x4[f4] : (f4_t){0.f, 0.f, 0.f, 0.f};
    }
}

// Compute one half-channel stage: scan 8 columns, epilogue, store.
// h must be a compile-time constant at each call.
__device__ __forceinline__ void compute_half(const f4_t (&v)[HALF], f4_t* __restrict__ o4,
                                             int lane, float Al, float& e,
                                             int h, bool store_ok) {
    constexpr float CD[6] = { fpow(A_1, 4),  fpow(A_1, 8),  fpow(A_1, 16),
                              fpow(A_1, 32), fpow(A_1, 64), fpow(A_1, 128) };
    // per-chunk offset B (coefficient uniformly A_1^4)
    float B[HALF];
#pragma unroll
    for (int j = 0; j < HALF; ++j) {
        f4_t  r  = v[j];
        float b0 = (h == 0 && j == 0 && lane == 0) ? r.x : S_C * r.x;  // smooth[0]=x[0]
        B[j] = fmaf(A_3, b0, S_C * fmaf(A_2, r.y, fmaf(A_1, r.z, r.w)));
    }
    // inclusive wave scan: 6 shuffle steps x 8 independent columns
#pragma unroll
    for (int s = 0; s < 6; ++s) {
        const int   d  = 1 << s;
        const float cc = CD[s];
        float Bp[HALF];
#pragma unroll
        for (int j = 0; j < HALF; ++j) Bp[j] = __shfl_up(B[j], d);
        const bool ok = (lane >= d);
#pragma unroll
        for (int j = 0; j < HALF; ++j) B[j] = fmaf(cc, ok ? Bp[j] : 0.0f, B[j]);
    }
    // epilogue per column: exclusive shuffle, replay, pcen, nt-store
#pragma unroll
    for (int j = 0; j < HALF; ++j) {
        const int k  = h * HALF + j;
        float Tk = __shfl(B[j], 63);             // segment total
        float Bi = __shfl_up(B[j], 1);
        if (lane == 0) Bi = 0.0f;
        float sm = fmaf(Al, e, Bi);              // smoothed value entering chunk

        f4_t  r  = v[j];
        float b0 = (h == 0 && j == 0 && lane == 0) ? r.x : S_C * r.x;
        float s0 = fmaf(A_1, sm, b0);
        float s1 = fmaf(A_1, s0, S_C * r.y);
        float s2 = fmaf(A_1, s1, S_C * r.z);
        float s3 = fmaf(A_1, s2, S_C * r.w);

        f4_t o;
        o.x = pcen_elem(r.x, s0);
        o.y = pcen_elem(r.y, s1);
        o.z = pcen_elem(r.z, s2);
        o.w = pcen_elem(r.w, s3);

        const int f4 = lane + 64 * k;
        if (store_ok && f4 < NF4) __builtin_nontemporal_store(o, &o4[f4]);

        e = fmaf(A256, e, Tk);                   // advance to next segment
    }
}

__global__ __launch_bounds__(NTH) void pcen_kernel(const float* __restrict__ x,
                                                   float* __restrict__ out,
                                                   int nch) {
    const int lane = threadIdx.x & 63;
    const int wid  = blockIdx.x * (NTH / 64) + (threadIdx.x >> 6);
    const int nw   = gridDim.x * (NTH / 64);     // total waves = 4096
    const int c0   = wid;
    const int c1   = wid + nw;
    if (c0 >= nch) return;
    const bool has1 = (c1 < nch);

    const f4_t* __restrict__ x0 = (const f4_t*)(x + (size_t)c0 * TLEN);
    const f4_t* __restrict__ x1 = (const f4_t*)(x + (size_t)(has1 ? c1 : c0) * TLEN);
    f4_t*       __restrict__ o0 = (f4_t*)(out + (size_t)c0 * TLEN);
    f4_t*       __restrict__ o1 = (f4_t*)(out + (size_t)(has1 ? c1 : c0) * TLEN);

    const float Al = __builtin_amdgcn_exp2f((float)lane * L2A4);

    f4_t  va[HALF], vb[HALF];
    float e = 0.0f;

    // ---- steady-state pipeline over 4 half-channel stages ----
    load_half(va, x0, lane, 0);                   // stage 0 loads
    __builtin_amdgcn_sched_barrier(0);

    load_half(vb, x0, lane, 1);                   // stage 1 loads in flight
    __builtin_amdgcn_sched_barrier(0);
    compute_half(va, o0, lane, Al, e, 0, true);   // c0 half 0

    load_half(va, x1, lane, 0);                   // stage 2 loads in flight
    __builtin_amdgcn_sched_barrier(0);
    compute_half(vb, o0, lane, Al, e, 1, true);   // c0 half 1

    e = 0.0f;                                     // new channel
    load_half(vb, x1, lane, 1);                   // stage 3 loads in flight
    __builtin_amdgcn_sched_barrier(0);
    compute_half(va, o1, lane, Al, e, 0, has1);   // c1 half 0

    compute_half(vb, o1, lane, Al, e, 1, has1);   // c1 half 1
}

extern "C" void kernel_launch(void* const* d_in, const int* in_sizes, int n_in,
                              void* d_out, int out_size, void* d_ws, size_t ws_size,
                              hipStream_t stream) {
    const float* x   = (const float*)d_in[0];
    float*       out = (float*)d_out;
    const int nch    = in_sizes[0] / TLEN;               // 8192 channels
    const int wpb    = NTH / 64;                         // 4 waves per block
    const int nw     = (nch + 1) / 2;                    // 2 channels per wave
    const int grid   = (nw + wpb - 1) / wpb;             // 1024 blocks
    pcen_kernel<<<grid, NTH, 0, stream>>>(x, out, nch);
}